// Round 4
// baseline (300.866 us; speedup 1.0000x reference)
//
#include <hip/hip_runtime.h>
#include <stdint.h>

#define Bb 64
#define Hh 128
#define Ww 128
#define Cc 21
#define Pp 49152          // NUM_SAMPLED
#define Kk 36864          // NUM_UNCERTAIN
#define NR 12288          // NUM_RANDOM

#define BINS 2048         // 11-bit digits; u64 passes shift 16/27, then 9-bit top digit in u32
#define TILE 4096         // elements per sort tile
#define TILES 12          // Pp / TILE
#define NBLK (Bb * TILES) // 768 blocks

typedef uint32_t u32;
typedef uint64_t u64;
typedef unsigned short u16;

// XCD-affine decode: all TILES blocks of segment s have blk%8 == s%8, so the
// round-robin block->XCD dispatch keeps a segment's r/w window (and the
// fused sample's redundant plane staging) in ONE XCD's L2. Heuristic only.
#define DECODE_ST const int s = blk & 63; const int t = blk >> 6;

// 11-bit ballot digit-match: mask of lanes in this wave holding digit d.
__device__ __forceinline__ u64 match11(u32 d) {
    u64 m = ~0ull;
    #pragma unroll
    for (int bit = 0; bit < 11; ++bit) {
        u64 bl = __ballot((d >> bit) & 1u);
        m &= ((d >> bit) & 1u) ? bl : ~bl;
    }
    return m;
}

// ---------------------------------------------------------------------------
// Kernel 1 (fused extract+sample): stage ch-0 plane from logits in two
// row-halves (rows [0,65), then [64,128)); coords held in registers across
// both sweeps; each point handled in exactly one sweep (x0i>=64 partition;
// x1<=x0+1 keeps all 4 taps inside the staged half). key = fp32 bits of
// |interp| (order-isomorphic, non-negative); element = (key<<16)|idx; LSD
// stability supplies the idx tie-break matching jax.lax.top_k.
// fp contract OFF: bit-exact arithmetic required (one rank flip = O(1) err).
// Hist layout tile-major [s][t][d] (coalesced writes + prologue reads).
// ---------------------------------------------------------------------------
__global__ __launch_bounds__(256) void sample_key_kernel(const float* __restrict__ lg,
                                                         const float2* __restrict__ coords,
                                                         u64* __restrict__ keys,
                                                         u32* __restrict__ hist) {
#pragma clang fp contract(off)
    __shared__ float pl[65 * 128];     // 33,280 B (one row-half + 1 row)
    __shared__ u32 h[BINS];            // 8 KB
    const int tid = threadIdx.x;
    const int blk = blockIdx.x;
    DECODE_ST

    for (int i = tid; i < BINS; i += 256) h[i] = 0;
    const size_t pbase = (size_t)s * (Hh * Ww);
    float2 c[16];
    #pragma unroll
    for (int i = 0; i < 16; ++i) c[i] = coords[(size_t)s * Pp + t * TILE + i * 256 + tid];

    #pragma unroll 1
    for (int sweep = 0; sweep < 2; ++sweep) {
        if (sweep == 0) {
            // rows [0,65): 8320 px
            for (int i = tid; i < 8320; i += 256) pl[i] = lg[(pbase + i) * Cc];
        } else {
            __syncthreads();                         // sweep-0 readers done
            // rows [64,128): 8192 px
            for (int i = tid; i < 8192; i += 256) pl[i] = lg[(pbase + 8192 + i) * Cc];
        }
        __syncthreads();
        for (int i = 0; i < 16; ++i) {
            float xf = c[i].x * 127.0f;              // coords[...,0] -> H axis
            float yf = c[i].y * 127.0f;              // coords[...,1] -> W axis
            float x0 = floorf(xf), x1 = ceilf(xf);
            float y0 = floorf(yf), y1 = ceilf(yf);
            int x0i = (int)x0;
            if ((x0i >= 64 ? 1 : 0) != sweep) continue;   // exactly one sweep per point
            float mux = xf - x0;
            float muy = yf - y0;
            int rb  = x0i - sweep * 64;              // staged-row base
            int x1i = (int)x1 - sweep * 64;          // x1 <= x0+1 -> in staged half
            int y0i = (int)y0, y1i = (int)y1;
            float p1  = pl[rb  * Ww + y0i];
            float p2  = pl[x1i * Ww + y0i];
            float p3  = pl[rb  * Ww + y1i];
            float p4v = pl[x1i * Ww + y1i];
            float p12 = p1 * (1.0f - mux) + p2 * mux;
            float p34 = p3 * (1.0f - mux) + p4v * mux;
            float r   = p12 * (1.0f - muy) + p34 * muy;
            u32 kb = __float_as_uint(r) & 0x7fffffffu;   // |r| bits
            int idx = t * TILE + i * 256 + tid;
            keys[(size_t)s * Pp + idx] = ((u64)kb << 16) | (u32)idx;
            atomicAdd(&h[kb & (BINS - 1)], 1u);          // pass-0 digit
        }
    }
    __syncthreads();
    const size_t hbase = ((size_t)s * TILES + t) * BINS;
    #pragma unroll
    for (int j = 0; j < 8; ++j) {
        int d = j * 256 + tid;
        hist[hbase + d] = h[d];
    }
}

// ---------------------------------------------------------------------------
// Hist kernels: per-tile histogram via per-wave privatized LDS counters +
// atomicAdd. Output layout [s][t][d] (tile-major, coalesced).
// ---------------------------------------------------------------------------
__global__ __launch_bounds__(256) void hist64_kernel(const u64* __restrict__ in,
                                                     u32* __restrict__ hist, int shift) {
    __shared__ u32 h[4][BINS];         // 32 KB
    const int tid = threadIdx.x;
    const int w = tid >> 6;
    const int blk = blockIdx.x;
    DECODE_ST
    for (int i = tid; i < 4 * BINS; i += 256) ((u32*)h)[i] = 0;
    __syncthreads();
    const u64* src = in + (size_t)s * Pp + t * TILE;
    #pragma unroll 4
    for (int i = 0; i < 16; ++i) {
        u64 v = src[i * 256 + tid];
        atomicAdd(&h[w][(u32)(v >> shift) & (BINS - 1)], 1u);
    }
    __syncthreads();
    const size_t hbase = ((size_t)s * TILES + t) * BINS;
    #pragma unroll
    for (int j = 0; j < 8; ++j) {
        int d = j * 256 + tid;
        hist[hbase + d] = h[0][d] + h[1][d] + h[2][d] + h[3][d];
    }
}

__global__ __launch_bounds__(256) void hist32_kernel(const u32* __restrict__ in,
                                                     u32* __restrict__ hist) {
    __shared__ u32 h[4][BINS];         // 32 KB
    const int tid = threadIdx.x;
    const int w = tid >> 6;
    const int blk = blockIdx.x;
    DECODE_ST
    for (int i = tid; i < 4 * BINS; i += 256) ((u32*)h)[i] = 0;
    __syncthreads();
    const u32* src = in + (size_t)s * Pp + t * TILE;
    #pragma unroll 4
    for (int i = 0; i < 16; ++i) {
        u32 v = src[i * 256 + tid];
        atomicAdd(&h[w][(v >> 16) & (BINS - 1)], 1u);  // 9-bit digit; bins>=512 stay 0
    }
    __syncthreads();
    const size_t hbase = ((size_t)s * TILES + t) * BINS;
    #pragma unroll
    for (int j = 0; j < 8; ++j) {
        int d = j * 256 + tid;
        hist[hbase + d] = h[0][d] + h[1][d] + h[2][d] + h[3][d];
    }
}

// ---------------------------------------------------------------------------
// Offset derivation (shared): raw per-tile hist [s][t][d] ->
//   off[s][d][t] = sum_{d'<d} segtot[d'] + sum_{t'<t} cnt[d][t']
// Segment totals/prefixes staged in scan scratch (first 16 KB of el, dead
// until phase B); dual block-scan packed in u64 (local count low word,
// segment count high word; both < 2^32, no cross-carry).
// ---------------------------------------------------------------------------
__device__ __forceinline__ void fill_seg_tables(u32* sc1v, u32* sc2v, const u32* hb,
                                                int t, int tid) {
    #pragma unroll
    for (int j = 0; j < 8; ++j) {
        int d = j * 256 + tid;
        u32 tot = 0, pre = 0;
        #pragma unroll
        for (int tt = 0; tt < TILES; ++tt) {
            u32 cv = hb[tt * BINS + d];     // coalesced, L2-hot
            tot += cv;
            pre += (tt < t) ? cv : 0;
        }
        sc1v[d] = tot;
        sc2v[d] = pre;
    }
}

__device__ __forceinline__ void block_scan(const u32* sc1v, const u32* sc2v,
                                           u16* wh, u16* dl, u64* aux,
                                           int tid, int lane, int w) {
    const int d0 = tid * 8;
    u32 dtot[8], gtot[8], gpre[8];
    u32 t8l = 0, t8g = 0;
    #pragma unroll
    for (int j = 0; j < 8; ++j) {
        int d = d0 + j;
        u32 cv = (u32)wh[d * 4 + 0] + wh[d * 4 + 1] + wh[d * 4 + 2] + wh[d * 4 + 3];
        dtot[j] = cv; t8l += cv;
        gtot[j] = sc1v[d]; gpre[j] = sc2v[d]; t8g += gtot[j];
    }
    u64 own = ((u64)t8g << 32) | t8l;
    u64 sc = own;
    for (int o = 1; o < 64; o <<= 1) {
        u64 n = __shfl_up((unsigned long long)sc, o);
        if (lane >= o) sc += n;
    }
    if (lane == 63) aux[w] = sc;
    __syncthreads();
    if (tid == 0) {
        u64 run = 0;
        for (int i = 0; i < 4; ++i) { u64 x = aux[i]; aux[i] = run; run += x; }
    }
    __syncthreads();
    u64 excl = sc - own + aux[w];
    u32 run_l = (u32)excl;                  // local exclusive base
    u32 run_g = (u32)(excl >> 32);          // segment digit-exclusive base
    #pragma unroll
    for (int j = 0; j < 8; ++j) {
        int d = d0 + j;
        u32 ls = run_l;
        u32 g = run_g + gpre[j];            // off[s][d][t]
        dl[d] = (u16)(g - ls);
        u32 c0 = wh[d * 4 + 0], c1 = wh[d * 4 + 1], c2 = wh[d * 4 + 2];
        wh[d * 4 + 0] = (u16)ls;
        wh[d * 4 + 1] = (u16)(ls + c0);
        wh[d * 4 + 2] = (u16)(ls + c0 + c1);
        wh[d * 4 + 3] = (u16)(ls + c0 + c1 + c2);
        run_l += dtot[j];
        run_g += gtot[j];
    }
}

// ---------------------------------------------------------------------------
// Scatter (u64 passes 0,1): stable LDS reorder + run-contiguous global write.
// match11 once per element; cached ranks reused in phase B. compress=1
// (pass 1): emit u32 (top9<<16)|idx — digit bits [16,38) are spent; halves
// pass-2 traffic and LDS.
// ---------------------------------------------------------------------------
__global__ __launch_bounds__(256) void scatter64_kernel(const u64* __restrict__ in,
                                                        void* __restrict__ outbuf,
                                                        const u32* __restrict__ hist,
                                                        int shift, int compress) {
    __shared__ u64 el[TILE];           // 32 KB (first 16 KB = scan scratch pre-B)
    __shared__ u16 wh[BINS * 4];       // 16 KB
    __shared__ u16 dl[BINS];           // 4 KB
    __shared__ u64 aux[4];
    const int tid = threadIdx.x;
    const int lane = tid & 63;
    const int w = tid >> 6;
    const int blk = blockIdx.x;
    DECODE_ST
    const u64* src = in + (size_t)s * Pp + t * TILE;

    for (int i = tid; i < BINS * 4; i += 256) wh[i] = 0;
    u64 v[16];
    #pragma unroll
    for (int i = 0; i < 16; ++i) v[i] = src[w * 1024 + i * 64 + lane];
    fill_seg_tables((u32*)el, (u32*)el + BINS, hist + (size_t)s * (TILES * BINS), t, tid);
    __syncthreads();

    const u64 ltmask = (1ull << lane) - 1ull;
    u32 dg[16], pk[16];
    volatile u16* vwh = wh;
    #pragma unroll 2
    for (int i = 0; i < 16; ++i) {
        u32 d = (u32)(v[i] >> shift) & (BINS - 1);
        u64 m = match11(d);
        u32 before = (u32)__popcll(m & ltmask);
        u32 cnt = (u32)__popcll(m);
        bool lead = (lane == __ffsll((unsigned long long)m) - 1);
        dg[i] = d;
        pk[i] = before | (cnt << 8) | (lead ? 0x10000u : 0u);
        if (lead) { u32 p = d * 4 + w; vwh[p] = (u16)(vwh[p] + cnt); }
    }
    __syncthreads();
    block_scan((const u32*)el, (const u32*)el + BINS, wh, dl, aux, tid, lane, w);
    __syncthreads();

    for (int i = 0; i < 16; ++i) {
        u32 d = dg[i];
        u32 before = pk[i] & 0xffu;
        u32 base = vwh[d * 4 + w];
        el[base + before] = v[i];
        if (pk[i] & 0x10000u) vwh[d * 4 + w] = (u16)(base + ((pk[i] >> 8) & 0xffu));
    }
    __syncthreads();

    if (!compress) {
        u64* dst = (u64*)outbuf + (size_t)s * Pp;
        for (int i = 0; i < 16; ++i) {
            int pos = i * 256 + tid;
            u64 e = el[pos];
            u32 d = (u32)(e >> shift) & (BINS - 1);
            u32 g = (u32)(u16)(pos + dl[d]);
            dst[g] = e;
        }
    } else {
        u32* dst = (u32*)outbuf + (size_t)s * Pp;
        for (int i = 0; i < 16; ++i) {
            int pos = i * 256 + tid;
            u64 e = el[pos];
            u32 d = (u32)(e >> shift) & (BINS - 1);
            u32 g = (u32)(u16)(pos + dl[d]);
            dst[g] = ((u32)(e >> 38) << 16) | (u32)(e & 0xffffu);
        }
    }
}

// ---------------------------------------------------------------------------
// Final scatter (u32, 9-bit digit): rank -> g; emit out[s][g] = coords[s][idx]
// for g < K; fused extra_random copy into rows [K, P).
// ---------------------------------------------------------------------------
__global__ __launch_bounds__(256) void scatter32_final_kernel(const u32* __restrict__ in,
                                                              const u32* __restrict__ hist,
                                                              const float2* __restrict__ coords,
                                                              const float2* __restrict__ extra,
                                                              float2* __restrict__ out) {
    __shared__ u32 el32[TILE];         // 16 KB (first 16 KB = scan scratch pre-B)
    __shared__ u16 wh[BINS * 4];       // 16 KB
    __shared__ u16 dl[BINS];           // 4 KB
    __shared__ u64 aux[4];
    const int tid = threadIdx.x;
    const int lane = tid & 63;
    const int w = tid >> 6;
    const int blk = blockIdx.x;
    DECODE_ST
    const u32* src = in + (size_t)s * Pp + t * TILE;

    for (int i = tid; i < BINS * 4; i += 256) wh[i] = 0;
    u32 v[16];
    #pragma unroll
    for (int i = 0; i < 16; ++i) v[i] = src[w * 1024 + i * 64 + lane];
    fill_seg_tables((u32*)el32, (u32*)el32 + BINS, hist + (size_t)s * (TILES * BINS), t, tid);
    __syncthreads();

    const u64 ltmask = (1ull << lane) - 1ull;
    u32 dg[16], pk[16];
    volatile u16* vwh = wh;
    #pragma unroll 2
    for (int i = 0; i < 16; ++i) {
        u32 d = (v[i] >> 16) & (BINS - 1);
        u64 m = match11(d);
        u32 before = (u32)__popcll(m & ltmask);
        u32 cnt = (u32)__popcll(m);
        bool lead = (lane == __ffsll((unsigned long long)m) - 1);
        dg[i] = d;
        pk[i] = before | (cnt << 8) | (lead ? 0x10000u : 0u);
        if (lead) { u32 p = d * 4 + w; vwh[p] = (u16)(vwh[p] + cnt); }
    }
    __syncthreads();
    block_scan((const u32*)el32, (const u32*)el32 + BINS, wh, dl, aux, tid, lane, w);
    __syncthreads();

    for (int i = 0; i < 16; ++i) {
        u32 d = dg[i];
        u32 before = pk[i] & 0xffu;
        u32 base = vwh[d * 4 + w];
        el32[base + before] = v[i];
        if (pk[i] & 0x10000u) vwh[d * 4 + w] = (u16)(base + ((pk[i] >> 8) & 0xffu));
    }
    __syncthreads();

    const float2* cseg = coords + (size_t)s * Pp;
    float2* oseg = out + (size_t)s * Pp;
    for (int i = 0; i < 16; ++i) {
        int pos = i * 256 + tid;
        u32 e = el32[pos];
        u32 d = (e >> 16) & (BINS - 1);
        u32 g = (u32)(u16)(pos + dl[d]);
        if (g < Kk) oseg[g] = cseg[e & 0xffffu];
    }
    const float2* eseg = extra + (size_t)s * NR;
    float2* xseg = out + (size_t)s * Pp + Kk;
    #pragma unroll
    for (int i = 0; i < 4; ++i) {
        int p = t * 1024 + i * 256 + tid;
        xseg[p] = eseg[p];
    }
}

extern "C" void kernel_launch(void* const* d_in, const int* in_sizes, int n_in,
                              void* d_out, int out_size, void* d_ws, size_t ws_size,
                              hipStream_t stream) {
    (void)in_sizes; (void)n_in; (void)out_size; (void)ws_size;
    const float*  logits = (const float*)d_in[0];   // (B,H,W,C) fp32
    const float2* coords = (const float2*)d_in[1];  // (B,P,2)  fp32
    const float2* extra  = (const float2*)d_in[2];  // (B,NR,2) fp32
    float2* out = (float2*)d_out;

    u64* buf0 = (u64*)d_ws;                          // 25.2 MB
    u64* buf1 = buf0 + (size_t)Bb * Pp;              // 25.2 MB (ping-pong)
    u32* histA = (u32*)d_out;                        // 6.3 MB scratch (passes 0,1); final pass overwrites all of out
    u32* histB = (u32*)buf1;                         // pass-2 hist; buf1 keys dead after pass-1 scatter

    // fused extract+sample: logits,coords -> keys(buf0,u64) + pass-0 hist
    sample_key_kernel<<<NBLK, 256, 0, stream>>>(logits, coords, buf0, histA);
    // pass 0: bits [16,27)  buf0(u64) -> buf1(u64)
    scatter64_kernel<<<NBLK, 256, 0, stream>>>(buf0, buf1, histA, 16, 0);
    // pass 1: bits [27,38)  buf1(u64) -> buf0(u32 compressed: top9|idx)
    hist64_kernel<<<NBLK, 256, 0, stream>>>(buf1, histA, 27);
    scatter64_kernel<<<NBLK, 256, 0, stream>>>(buf1, buf0, histA, 27, 1);
    // pass 2: 9-bit top digit  buf0(u32) -> out (fused gather+emit+extra)
    hist32_kernel<<<NBLK, 256, 0, stream>>>((const u32*)buf0, histB);
    scatter32_final_kernel<<<NBLK, 256, 0, stream>>>((const u32*)buf0, histB, coords, extra, out);
}

// Round 5
// 283.131 us; speedup vs baseline: 1.0626x; 1.0626x over previous
//
#include <hip/hip_runtime.h>
#include <stdint.h>

#define Bb 64
#define Hh 128
#define Ww 128
#define Cc 21
#define Pp 49152          // NUM_SAMPLED
#define Kk 36864          // NUM_UNCERTAIN
#define NR 12288          // NUM_RANDOM

#define BINS 2048         // 11-bit digits; u64 passes shift 16/27, then 9-bit top digit in u32
#define TILE 4096         // elements per sort tile
#define TILES 12          // Pp / TILE
#define NBLK (Bb * TILES) // 768 blocks

typedef uint32_t u32;
typedef uint64_t u64;
typedef unsigned short u16;

// XCD-affine decode: all TILES blocks of segment s have blk%8 == s%8, so the
// round-robin block->XCD dispatch keeps a segment's r/w window (and the
// sample's redundant plane staging) in ONE XCD's L2. Heuristic only.
#define DECODE_ST const int s = blk & 63; const int t = blk >> 6;

// 11-bit ballot digit-match: mask of lanes in this wave holding digit d.
__device__ __forceinline__ u64 match11(u32 d) {
    u64 m = ~0ull;
    #pragma unroll
    for (int bit = 0; bit < 11; ++bit) {
        u64 bl = __ballot((d >> bit) & 1u);
        m &= ((d >> bit) & 1u) ? bl : ~bl;
    }
    return m;
}

// ---------------------------------------------------------------------------
// Kernel 0: vectorized ch-0 extract. Dense float4 reads of the whole logits
// array (fully coalesced — the R4 lesson: 84B-strided scalar reads are
// latency-bound at ~1.8 TB/s; dense float4 hits ~6 TB/s). Each float4
// [4g,4g+4) contains at most one ch-0 element (21k in range); write it to
// planes[k]. Writes are monotone-dense (~16/21 lanes, adjacent k) -> well
// coalesced, 4 MB total. 1024 blocks x 256 thr x 21 float4 = exact cover.
// ---------------------------------------------------------------------------
__global__ __launch_bounds__(256) void extract_kernel(const float* __restrict__ lg,
                                                      float* __restrict__ planes) {
    const u32 gtid = blockIdx.x * 256 + threadIdx.x;   // [0, 262144)
    const float4* l4 = (const float4*)lg;
    #pragma unroll
    for (u32 it = 0; it < 21; ++it) {
        u32 g = it * 262144u + gtid;                   // [0, 5505024)
        float4 v = l4[g];
        u32 base = g * 4u;
        u32 k = (base + 20u) / 21u;                    // ceil(base/21): first px with ch0 >= base
        u32 pos = k * 21u - base;
        if (pos < 4u) {
            float val = (pos == 0u) ? v.x : (pos == 1u) ? v.y : (pos == 2u) ? v.z : v.w;
            planes[k] = val;
        }
    }
}

// ---------------------------------------------------------------------------
// Kernel 1: bilinear sample (64 KB compact plane staged in LDS via float4),
// build sortable key, fused pass-0 per-tile histogram. key = fp32 bits of
// |interp| (order-isomorphic for non-negative floats); element =
// (key<<16)|idx; LSD stability supplies the idx tie-break (jax.lax.top_k).
// fp contract OFF: bit-exact arithmetic required (one rank flip = O(1) err).
// Hist layout tile-major [s][t][d] (coalesced writes + scatter-prologue reads).
// ---------------------------------------------------------------------------
__global__ __launch_bounds__(256) void sample_key_kernel(const float* __restrict__ planes,
                                                         const float2* __restrict__ coords,
                                                         u64* __restrict__ keys,
                                                         u32* __restrict__ hist) {
#pragma clang fp contract(off)
    __shared__ float pl[Hh * Ww];      // 64 KB
    __shared__ u32 h[BINS];            // 8 KB
    const int tid = threadIdx.x;
    const int blk = blockIdx.x;
    DECODE_ST

    for (int i = tid; i < BINS; i += 256) h[i] = 0;
    const float4* p4 = (const float4*)(planes + s * (Hh * Ww));
    float4* l4 = (float4*)pl;
    #pragma unroll
    for (int i = 0; i < 16; ++i) l4[i * 256 + tid] = p4[i * 256 + tid];
    __syncthreads();

    #pragma unroll 4
    for (int i = 0; i < 16; ++i) {
        int idx = t * TILE + i * 256 + tid;            // point index within segment
        int gid = s * Pp + idx;
        float2 c = coords[gid];
        float xf = c.x * 127.0f;                       // coords[...,0] -> H axis
        float yf = c.y * 127.0f;                       // coords[...,1] -> W axis
        float x0 = floorf(xf), x1 = ceilf(xf);
        float y0 = floorf(yf), y1 = ceilf(yf);
        float mux = xf - x0;
        float muy = yf - y0;
        int x0i = (int)x0, x1i = (int)x1, y0i = (int)y0, y1i = (int)y1;
        float p1  = pl[x0i * Ww + y0i];
        float p2  = pl[x1i * Ww + y0i];
        float p3  = pl[x0i * Ww + y1i];
        float p4v = pl[x1i * Ww + y1i];
        float p12 = p1 * (1.0f - mux) + p2 * mux;
        float p34 = p3 * (1.0f - mux) + p4v * mux;
        float r   = p12 * (1.0f - muy) + p34 * muy;
        u32 kb = __float_as_uint(r) & 0x7fffffffu;     // |r| bits
        keys[gid] = ((u64)kb << 16) | (u32)idx;
        atomicAdd(&h[kb & (BINS - 1)], 1u);            // pass-0 digit (uniform)
    }
    __syncthreads();
    const size_t hbase = ((size_t)s * TILES + t) * BINS;
    #pragma unroll
    for (int j = 0; j < 8; ++j) {
        int d = j * 256 + tid;
        hist[hbase + d] = h[d];
    }
}

// ---------------------------------------------------------------------------
// Hist kernels: per-tile histogram via per-wave privatized LDS counters +
// atomicAdd. Output layout [s][t][d] (tile-major, coalesced).
// ---------------------------------------------------------------------------
__global__ __launch_bounds__(256) void hist64_kernel(const u64* __restrict__ in,
                                                     u32* __restrict__ hist, int shift) {
    __shared__ u32 h[4][BINS];         // 32 KB
    const int tid = threadIdx.x;
    const int w = tid >> 6;
    const int blk = blockIdx.x;
    DECODE_ST
    for (int i = tid; i < 4 * BINS; i += 256) ((u32*)h)[i] = 0;
    __syncthreads();
    const u64* src = in + (size_t)s * Pp + t * TILE;
    #pragma unroll 4
    for (int i = 0; i < 16; ++i) {
        u64 v = src[i * 256 + tid];
        atomicAdd(&h[w][(u32)(v >> shift) & (BINS - 1)], 1u);
    }
    __syncthreads();
    const size_t hbase = ((size_t)s * TILES + t) * BINS;
    #pragma unroll
    for (int j = 0; j < 8; ++j) {
        int d = j * 256 + tid;
        hist[hbase + d] = h[0][d] + h[1][d] + h[2][d] + h[3][d];
    }
}

__global__ __launch_bounds__(256) void hist32_kernel(const u32* __restrict__ in,
                                                     u32* __restrict__ hist) {
    __shared__ u32 h[4][BINS];         // 32 KB
    const int tid = threadIdx.x;
    const int w = tid >> 6;
    const int blk = blockIdx.x;
    DECODE_ST
    for (int i = tid; i < 4 * BINS; i += 256) ((u32*)h)[i] = 0;
    __syncthreads();
    const u32* src = in + (size_t)s * Pp + t * TILE;
    #pragma unroll 4
    for (int i = 0; i < 16; ++i) {
        u32 v = src[i * 256 + tid];
        atomicAdd(&h[w][(v >> 16) & (BINS - 1)], 1u);  // 9-bit digit; bins>=512 stay 0
    }
    __syncthreads();
    const size_t hbase = ((size_t)s * TILES + t) * BINS;
    #pragma unroll
    for (int j = 0; j < 8; ++j) {
        int d = j * 256 + tid;
        hist[hbase + d] = h[0][d] + h[1][d] + h[2][d] + h[3][d];
    }
}

// ---------------------------------------------------------------------------
// Offset derivation (shared): raw per-tile hist [s][t][d] ->
//   off[s][d][t] = sum_{d'<d} segtot[d'] + sum_{t'<t} cnt[d][t']
// Segment totals/prefixes staged in scan scratch (first 16 KB of el, dead
// until phase B); dual block-scan packed in u64 (local count low word,
// segment count high word; both < 2^32, no cross-carry).
// ---------------------------------------------------------------------------
__device__ __forceinline__ void fill_seg_tables(u32* sc1v, u32* sc2v, const u32* hb,
                                                int t, int tid) {
    #pragma unroll
    for (int j = 0; j < 8; ++j) {
        int d = j * 256 + tid;
        u32 tot = 0, pre = 0;
        #pragma unroll
        for (int tt = 0; tt < TILES; ++tt) {
            u32 cv = hb[tt * BINS + d];     // coalesced, L2-hot
            tot += cv;
            pre += (tt < t) ? cv : 0;
        }
        sc1v[d] = tot;
        sc2v[d] = pre;
    }
}

__device__ __forceinline__ void block_scan(const u32* sc1v, const u32* sc2v,
                                           u16* wh, u16* dl, u64* aux,
                                           int tid, int lane, int w) {
    const int d0 = tid * 8;
    u32 dtot[8], gtot[8], gpre[8];
    u32 t8l = 0, t8g = 0;
    #pragma unroll
    for (int j = 0; j < 8; ++j) {
        int d = d0 + j;
        u32 cv = (u32)wh[d * 4 + 0] + wh[d * 4 + 1] + wh[d * 4 + 2] + wh[d * 4 + 3];
        dtot[j] = cv; t8l += cv;
        gtot[j] = sc1v[d]; gpre[j] = sc2v[d]; t8g += gtot[j];
    }
    u64 own = ((u64)t8g << 32) | t8l;
    u64 sc = own;
    for (int o = 1; o < 64; o <<= 1) {
        u64 n = __shfl_up((unsigned long long)sc, o);
        if (lane >= o) sc += n;
    }
    if (lane == 63) aux[w] = sc;
    __syncthreads();
    if (tid == 0) {
        u64 run = 0;
        for (int i = 0; i < 4; ++i) { u64 x = aux[i]; aux[i] = run; run += x; }
    }
    __syncthreads();
    u64 excl = sc - own + aux[w];
    u32 run_l = (u32)excl;                  // local exclusive base
    u32 run_g = (u32)(excl >> 32);          // segment digit-exclusive base
    #pragma unroll
    for (int j = 0; j < 8; ++j) {
        int d = d0 + j;
        u32 ls = run_l;
        u32 g = run_g + gpre[j];            // off[s][d][t]
        dl[d] = (u16)(g - ls);
        u32 c0 = wh[d * 4 + 0], c1 = wh[d * 4 + 1], c2 = wh[d * 4 + 2];
        wh[d * 4 + 0] = (u16)ls;
        wh[d * 4 + 1] = (u16)(ls + c0);
        wh[d * 4 + 2] = (u16)(ls + c0 + c1);
        wh[d * 4 + 3] = (u16)(ls + c0 + c1 + c2);
        run_l += dtot[j];
        run_g += gtot[j];
    }
}

// ---------------------------------------------------------------------------
// Scatter (u64 passes 0,1): stable LDS reorder + run-contiguous global write.
// match11 once per element; cached ranks reused in phase B. compress=1
// (pass 1): emit u32 (top9<<16)|idx — digit bits [16,38) are spent; halves
// pass-2 traffic and LDS.
// ---------------------------------------------------------------------------
__global__ __launch_bounds__(256) void scatter64_kernel(const u64* __restrict__ in,
                                                        void* __restrict__ outbuf,
                                                        const u32* __restrict__ hist,
                                                        int shift, int compress) {
    __shared__ u64 el[TILE];           // 32 KB (first 16 KB = scan scratch pre-B)
    __shared__ u16 wh[BINS * 4];       // 16 KB
    __shared__ u16 dl[BINS];           // 4 KB
    __shared__ u64 aux[4];
    const int tid = threadIdx.x;
    const int lane = tid & 63;
    const int w = tid >> 6;
    const int blk = blockIdx.x;
    DECODE_ST
    const u64* src = in + (size_t)s * Pp + t * TILE;

    for (int i = tid; i < BINS * 4; i += 256) wh[i] = 0;
    u64 v[16];
    #pragma unroll
    for (int i = 0; i < 16; ++i) v[i] = src[w * 1024 + i * 64 + lane];
    fill_seg_tables((u32*)el, (u32*)el + BINS, hist + (size_t)s * (TILES * BINS), t, tid);
    __syncthreads();

    const u64 ltmask = (1ull << lane) - 1ull;
    u32 dg[16], pk[16];
    volatile u16* vwh = wh;
    #pragma unroll 2
    for (int i = 0; i < 16; ++i) {
        u32 d = (u32)(v[i] >> shift) & (BINS - 1);
        u64 m = match11(d);
        u32 before = (u32)__popcll(m & ltmask);
        u32 cnt = (u32)__popcll(m);
        bool lead = (lane == __ffsll((unsigned long long)m) - 1);
        dg[i] = d;
        pk[i] = before | (cnt << 8) | (lead ? 0x10000u : 0u);
        if (lead) { u32 p = d * 4 + w; vwh[p] = (u16)(vwh[p] + cnt); }
    }
    __syncthreads();
    block_scan((const u32*)el, (const u32*)el + BINS, wh, dl, aux, tid, lane, w);
    __syncthreads();

    for (int i = 0; i < 16; ++i) {
        u32 d = dg[i];
        u32 before = pk[i] & 0xffu;
        u32 base = vwh[d * 4 + w];
        el[base + before] = v[i];
        if (pk[i] & 0x10000u) vwh[d * 4 + w] = (u16)(base + ((pk[i] >> 8) & 0xffu));
    }
    __syncthreads();

    if (!compress) {
        u64* dst = (u64*)outbuf + (size_t)s * Pp;
        for (int i = 0; i < 16; ++i) {
            int pos = i * 256 + tid;
            u64 e = el[pos];
            u32 d = (u32)(e >> shift) & (BINS - 1);
            u32 g = (u32)(u16)(pos + dl[d]);
            dst[g] = e;
        }
    } else {
        u32* dst = (u32*)outbuf + (size_t)s * Pp;
        for (int i = 0; i < 16; ++i) {
            int pos = i * 256 + tid;
            u64 e = el[pos];
            u32 d = (u32)(e >> shift) & (BINS - 1);
            u32 g = (u32)(u16)(pos + dl[d]);
            dst[g] = ((u32)(e >> 38) << 16) | (u32)(e & 0xffffu);
        }
    }
}

// ---------------------------------------------------------------------------
// Final scatter (u32, 9-bit digit): rank -> g; emit out[s][g] = coords[s][idx]
// for g < K; fused extra_random copy into rows [K, P).
// ---------------------------------------------------------------------------
__global__ __launch_bounds__(256) void scatter32_final_kernel(const u32* __restrict__ in,
                                                              const u32* __restrict__ hist,
                                                              const float2* __restrict__ coords,
                                                              const float2* __restrict__ extra,
                                                              float2* __restrict__ out) {
    __shared__ u32 el32[TILE];         // 16 KB (= scan scratch pre-B)
    __shared__ u16 wh[BINS * 4];       // 16 KB
    __shared__ u16 dl[BINS];           // 4 KB
    __shared__ u64 aux[4];
    const int tid = threadIdx.x;
    const int lane = tid & 63;
    const int w = tid >> 6;
    const int blk = blockIdx.x;
    DECODE_ST
    const u32* src = in + (size_t)s * Pp + t * TILE;

    for (int i = tid; i < BINS * 4; i += 256) wh[i] = 0;
    u32 v[16];
    #pragma unroll
    for (int i = 0; i < 16; ++i) v[i] = src[w * 1024 + i * 64 + lane];
    fill_seg_tables((u32*)el32, (u32*)el32 + BINS, hist + (size_t)s * (TILES * BINS), t, tid);
    __syncthreads();

    const u64 ltmask = (1ull << lane) - 1ull;
    u32 dg[16], pk[16];
    volatile u16* vwh = wh;
    #pragma unroll 2
    for (int i = 0; i < 16; ++i) {
        u32 d = (v[i] >> 16) & (BINS - 1);
        u64 m = match11(d);
        u32 before = (u32)__popcll(m & ltmask);
        u32 cnt = (u32)__popcll(m);
        bool lead = (lane == __ffsll((unsigned long long)m) - 1);
        dg[i] = d;
        pk[i] = before | (cnt << 8) | (lead ? 0x10000u : 0u);
        if (lead) { u32 p = d * 4 + w; vwh[p] = (u16)(vwh[p] + cnt); }
    }
    __syncthreads();
    block_scan((const u32*)el32, (const u32*)el32 + BINS, wh, dl, aux, tid, lane, w);
    __syncthreads();

    for (int i = 0; i < 16; ++i) {
        u32 d = dg[i];
        u32 before = pk[i] & 0xffu;
        u32 base = vwh[d * 4 + w];
        el32[base + before] = v[i];
        if (pk[i] & 0x10000u) vwh[d * 4 + w] = (u16)(base + ((pk[i] >> 8) & 0xffu));
    }
    __syncthreads();

    const float2* cseg = coords + (size_t)s * Pp;
    float2* oseg = out + (size_t)s * Pp;
    for (int i = 0; i < 16; ++i) {
        int pos = i * 256 + tid;
        u32 e = el32[pos];
        u32 d = (e >> 16) & (BINS - 1);
        u32 g = (u32)(u16)(pos + dl[d]);
        if (g < Kk) oseg[g] = cseg[e & 0xffffu];
    }
    const float2* eseg = extra + (size_t)s * NR;
    float2* xseg = out + (size_t)s * Pp + Kk;
    #pragma unroll
    for (int i = 0; i < 4; ++i) {
        int p = t * 1024 + i * 256 + tid;
        xseg[p] = eseg[p];
    }
}

extern "C" void kernel_launch(void* const* d_in, const int* in_sizes, int n_in,
                              void* d_out, int out_size, void* d_ws, size_t ws_size,
                              hipStream_t stream) {
    (void)in_sizes; (void)n_in; (void)out_size; (void)ws_size;
    const float*  logits = (const float*)d_in[0];   // (B,H,W,C) fp32
    const float2* coords = (const float2*)d_in[1];  // (B,P,2)  fp32
    const float2* extra  = (const float2*)d_in[2];  // (B,NR,2) fp32
    float2* out = (float2*)d_out;

    u64* buf0 = (u64*)d_ws;                          // 25.2 MB
    u64* buf1 = buf0 + (size_t)Bb * Pp;              // 25.2 MB (ping-pong)
    float* planes = (float*)buf1;                    // 4 MB; dead before pass-0 scatter writes buf1
    u32* histA = (u32*)d_out;                        // 6.3 MB scratch (passes 0,1); final pass overwrites all of out
    u32* histB = (u32*)buf1;                         // pass-2 hist; buf1 keys dead after pass-1 scatter

    // ch-0 extract (dense float4) -> compact planes
    extract_kernel<<<1024, 256, 0, stream>>>(logits, planes);
    // sample: planes,coords -> keys(buf0,u64) + pass-0 hist
    sample_key_kernel<<<NBLK, 256, 0, stream>>>(planes, coords, buf0, histA);
    // pass 0: bits [16,27)  buf0(u64) -> buf1(u64)
    scatter64_kernel<<<NBLK, 256, 0, stream>>>(buf0, buf1, histA, 16, 0);
    // pass 1: bits [27,38)  buf1(u64) -> buf0(u32 compressed: top9|idx)
    hist64_kernel<<<NBLK, 256, 0, stream>>>(buf1, histA, 27);
    scatter64_kernel<<<NBLK, 256, 0, stream>>>(buf1, buf0, histA, 27, 1);
    // pass 2: 9-bit top digit  buf0(u32) -> out (fused gather+emit+extra)
    hist32_kernel<<<NBLK, 256, 0, stream>>>((const u32*)buf0, histB);
    scatter32_final_kernel<<<NBLK, 256, 0, stream>>>((const u32*)buf0, histB, coords, extra, out);
}

// Round 7
// 270.345 us; speedup vs baseline: 1.1129x; 1.0473x over previous
//
#include <hip/hip_runtime.h>
#include <stdint.h>

#define Bb 64
#define Hh 128
#define Ww 128
#define Cc 21
#define Pp 49152          // NUM_SAMPLED
#define Kk 36864          // NUM_UNCERTAIN
#define NR 12288          // NUM_RANDOM

// Digit split 10/10/11 over key bits [16,47): passes 0,1 use 10-bit digits
// (runs of ~4 in the scatter -> half the scattered-write line traffic of the
// old 11/11/9 split); pass 2 gets the 11-bit exponent-dominated digit
// (bits [36,47)) which is highly skewed -> long runs -> coalesced anyway.
#define NB0 1024          // pass 0/1 bins
#define NB2 2048          // pass 2 bins
#define TILE 4096         // elements per sort tile
#define TILES 12          // Pp / TILE
#define NBLK (Bb * TILES) // 768 blocks

typedef uint32_t u32;
typedef uint64_t u64;
typedef unsigned short u16;

// XCD-affine decode: all TILES blocks of segment s have blk%8 == s%8, so the
// round-robin block->XCD dispatch keeps a segment's r/w window in ONE XCD's
// L2 (write-merging of the scattered radix stores happens in that L2).
// Performance heuristic only; correctness never depends on placement.
#define DECODE_ST const int s = blk & 63; const int t = blk >> 6;

// N-bit ballot digit-match: mask of lanes in this wave holding digit d.
template<int NBITS>
__device__ __forceinline__ u64 matchN(u32 d) {
    u64 m = ~0ull;
    #pragma unroll
    for (int bit = 0; bit < NBITS; ++bit) {
        u64 bl = __ballot((d >> bit) & 1u);
        m &= ((d >> bit) & 1u) ? bl : ~bl;
    }
    return m;
}

// ---------------------------------------------------------------------------
// Kernel 0: vectorized ch-0 extract. Dense float4 reads (R4 lesson: 84B-
// strided scalar reads are latency-bound at 1.8 TB/s; dense float4 ~6 TB/s).
// Each float4 [4g,4g+4) holds at most one ch-0 element; writes monotone-dense.
// ---------------------------------------------------------------------------
__global__ __launch_bounds__(256) void extract_kernel(const float* __restrict__ lg,
                                                      float* __restrict__ planes) {
    const u32 gtid = blockIdx.x * 256 + threadIdx.x;   // [0, 262144)
    const float4* l4 = (const float4*)lg;
    #pragma unroll
    for (u32 it = 0; it < 21; ++it) {
        u32 g = it * 262144u + gtid;                   // [0, 5505024)
        float4 v = l4[g];
        u32 base = g * 4u;
        u32 k = (base + 20u) / 21u;                    // first px with ch0 >= base
        u32 pos = k * 21u - base;
        if (pos < 4u) {
            float val = (pos == 0u) ? v.x : (pos == 1u) ? v.y : (pos == 2u) ? v.z : v.w;
            planes[k] = val;
        }
    }
}

// ---------------------------------------------------------------------------
// Kernel 1: bilinear sample (64 KB compact plane staged in LDS via float4),
// build sortable key, fused pass-0 (10-bit) per-tile histogram. key = fp32
// bits of |interp| (order-isomorphic, non-negative); element = (key<<16)|idx;
// LSD stability supplies the idx tie-break (jax.lax.top_k).
// fp contract OFF: bit-exact arithmetic required (one rank flip = O(1) err).
// Hist layout tile-major [s][t][d] (coalesced writes + scatter-prologue reads).
// ---------------------------------------------------------------------------
__global__ __launch_bounds__(256) void sample_key_kernel(const float* __restrict__ planes,
                                                         const float2* __restrict__ coords,
                                                         u64* __restrict__ keys,
                                                         u32* __restrict__ hist) {
#pragma clang fp contract(off)
    __shared__ float pl[Hh * Ww];      // 64 KB
    __shared__ u32 h[NB0];             // 4 KB
    const int tid = threadIdx.x;
    const int blk = blockIdx.x;
    DECODE_ST

    for (int i = tid; i < NB0; i += 256) h[i] = 0;
    const float4* p4 = (const float4*)(planes + (size_t)s * (Hh * Ww));
    float4* l4 = (float4*)pl;
    #pragma unroll
    for (int i = 0; i < 16; ++i) l4[i * 256 + tid] = p4[i * 256 + tid];
    __syncthreads();

    #pragma unroll 4
    for (int i = 0; i < 16; ++i) {
        int idx = t * TILE + i * 256 + tid;            // point index within segment
        int gid = s * Pp + idx;
        float2 c = coords[gid];
        float xf = c.x * 127.0f;                       // coords[...,0] -> H axis
        float yf = c.y * 127.0f;                       // coords[...,1] -> W axis
        float x0 = floorf(xf), x1 = ceilf(xf);
        float y0 = floorf(yf), y1 = ceilf(yf);
        float mux = xf - x0;
        float muy = yf - y0;
        int x0i = (int)x0, x1i = (int)x1, y0i = (int)y0, y1i = (int)y1;
        float p1  = pl[x0i * Ww + y0i];
        float p2  = pl[x1i * Ww + y0i];
        float p3  = pl[x0i * Ww + y1i];
        float p4v = pl[x1i * Ww + y1i];
        float p12 = p1 * (1.0f - mux) + p2 * mux;
        float p34 = p3 * (1.0f - mux) + p4v * mux;
        float r   = p12 * (1.0f - muy) + p34 * muy;
        u32 kb = __float_as_uint(r) & 0x7fffffffu;     // |r| bits
        keys[gid] = ((u64)kb << 16) | (u32)idx;
        atomicAdd(&h[kb & (NB0 - 1)], 1u);             // pass-0 digit (uniform)
    }
    __syncthreads();
    const size_t hbase = ((size_t)s * TILES + t) * NB0;
    #pragma unroll
    for (int j = 0; j < NB0 / 256; ++j) {
        int d = j * 256 + tid;
        hist[hbase + d] = h[d];
    }
}

// ---------------------------------------------------------------------------
// Hist kernels: per-tile histogram via per-wave privatized LDS counters +
// atomicAdd. Output layout [s][t][d] (tile-major, coalesced).
// ---------------------------------------------------------------------------
__global__ __launch_bounds__(256) void hist64_kernel(const u64* __restrict__ in,
                                                     u32* __restrict__ hist, int shift) {
    __shared__ u32 h[4][NB0];          // 16 KB
    const int tid = threadIdx.x;
    const int w = tid >> 6;
    const int blk = blockIdx.x;
    DECODE_ST
    for (int i = tid; i < 4 * NB0; i += 256) ((u32*)h)[i] = 0;
    __syncthreads();
    const u64* src = in + (size_t)s * Pp + t * TILE;
    #pragma unroll 4
    for (int i = 0; i < 16; ++i) {
        u64 v = src[i * 256 + tid];
        atomicAdd(&h[w][(u32)(v >> shift) & (NB0 - 1)], 1u);
    }
    __syncthreads();
    const size_t hbase = ((size_t)s * TILES + t) * NB0;
    #pragma unroll
    for (int j = 0; j < NB0 / 256; ++j) {
        int d = j * 256 + tid;
        hist[hbase + d] = h[0][d] + h[1][d] + h[2][d] + h[3][d];
    }
}

__global__ __launch_bounds__(256) void hist32_kernel(const u32* __restrict__ in,
                                                     u32* __restrict__ hist) {
    __shared__ u32 h[4][NB2];          // 32 KB
    const int tid = threadIdx.x;
    const int w = tid >> 6;
    const int blk = blockIdx.x;
    DECODE_ST
    for (int i = tid; i < 4 * NB2; i += 256) ((u32*)h)[i] = 0;
    __syncthreads();
    const u32* src = in + (size_t)s * Pp + t * TILE;
    #pragma unroll 4
    for (int i = 0; i < 16; ++i) {
        u32 v = src[i * 256 + tid];
        atomicAdd(&h[w][(v >> 16) & (NB2 - 1)], 1u);   // 11-bit top digit
    }
    __syncthreads();
    const size_t hbase = ((size_t)s * TILES + t) * NB2;
    #pragma unroll
    for (int j = 0; j < NB2 / 256; ++j) {
        int d = j * 256 + tid;
        hist[hbase + d] = h[0][d] + h[1][d] + h[2][d] + h[3][d];
    }
}

// ---------------------------------------------------------------------------
// Offset derivation (shared): raw per-tile hist [s][t][d] ->
//   off[s][d][t] = sum_{d'<d} segtot[d'] + sum_{t'<t} cnt[d][t']
// Segment totals/prefixes staged in scan scratch (inside el, dead until
// phase B); dual block-scan packed in u64 (local count low word, segment
// count high word; both < 2^32, no cross-carry).
// ---------------------------------------------------------------------------
template<int NB>
__device__ __forceinline__ void fill_seg_tables(u32* sc1v, u32* sc2v,
                                                const u32* hb, int t, int tid) {
    #pragma unroll
    for (int j = 0; j < NB / 256; ++j) {
        int d = j * 256 + tid;
        u32 tot = 0, pre = 0;
        #pragma unroll
        for (int tt = 0; tt < TILES; ++tt) {
            u32 cv = hb[tt * NB + d];       // coalesced, L2-hot
            tot += cv;
            pre += (tt < t) ? cv : 0;
        }
        sc1v[d] = tot;
        sc2v[d] = pre;
    }
}

template<int NB>
__device__ __forceinline__ void block_scan(const u32* sc1v, const u32* sc2v,
                                           u16* wh, u16* dl, u64* aux,
                                           int tid, int lane, int w) {
    constexpr int DPB = NB / 256;           // digits per thread
    const int d0 = tid * DPB;
    u32 dtot[DPB], gtot[DPB], gpre[DPB];
    u32 t8l = 0, t8g = 0;
    #pragma unroll
    for (int j = 0; j < DPB; ++j) {
        int d = d0 + j;
        u32 cv = (u32)wh[d * 4 + 0] + wh[d * 4 + 1] + wh[d * 4 + 2] + wh[d * 4 + 3];
        dtot[j] = cv; t8l += cv;
        gtot[j] = sc1v[d]; gpre[j] = sc2v[d]; t8g += gtot[j];
    }
    u64 own = ((u64)t8g << 32) | t8l;
    u64 sc = own;
    for (int o = 1; o < 64; o <<= 1) {
        u64 n = __shfl_up((unsigned long long)sc, o);
        if (lane >= o) sc += n;
    }
    if (lane == 63) aux[w] = sc;
    __syncthreads();
    if (tid == 0) {
        u64 run = 0;
        for (int i = 0; i < 4; ++i) { u64 x = aux[i]; aux[i] = run; run += x; }
    }
    __syncthreads();
    u64 excl = sc - own + aux[w];
    u32 run_l = (u32)excl;                  // local exclusive base
    u32 run_g = (u32)(excl >> 32);          // segment digit-exclusive base
    #pragma unroll
    for (int j = 0; j < DPB; ++j) {
        int d = d0 + j;
        u32 ls = run_l;
        u32 g = run_g + gpre[j];            // off[s][d][t]
        dl[d] = (u16)(g - ls);              // exact mod 2^16 (Pp < 65536)
        u32 c0 = wh[d * 4 + 0], c1 = wh[d * 4 + 1], c2 = wh[d * 4 + 2];
        wh[d * 4 + 0] = (u16)ls;
        wh[d * 4 + 1] = (u16)(ls + c0);
        wh[d * 4 + 2] = (u16)(ls + c0 + c1);
        wh[d * 4 + 3] = (u16)(ls + c0 + c1 + c2);
        run_l += dtot[j];
        run_g += gtot[j];
    }
}

// ---------------------------------------------------------------------------
// Scatter (u64 passes 0,1): stable LDS reorder + run-contiguous global write.
// matchN once per element; cached ranks reused in phase B. COMPRESS (pass 1):
// emit u32 (key[36,47)<<16)|idx — bits [16,36) are spent; halves pass-2
// traffic and LDS.
// ---------------------------------------------------------------------------
template<int NB, int SHIFT, bool COMPRESS>
__global__ __launch_bounds__(256) void scatter64_kernel(const u64* __restrict__ in,
                                                        void* __restrict__ outbuf,
                                                        const u32* __restrict__ hist) {
    __shared__ u64 el[TILE];           // 32 KB (head doubles as scan scratch pre-B)
    __shared__ u16 wh[NB * 4];         // 8 KB
    __shared__ u16 dl[NB];             // 2 KB
    __shared__ u64 aux[4];
    const int tid = threadIdx.x;
    const int lane = tid & 63;
    const int w = tid >> 6;
    const int blk = blockIdx.x;
    DECODE_ST
    const u64* src = in + (size_t)s * Pp + t * TILE;

    for (int i = tid; i < NB * 4; i += 256) wh[i] = 0;
    u64 v[16];
    #pragma unroll
    for (int i = 0; i < 16; ++i) v[i] = src[w * 1024 + i * 64 + lane];
    fill_seg_tables<NB>((u32*)el, (u32*)el + NB, hist + (size_t)s * (TILES * NB), t, tid);
    __syncthreads();

    const u64 ltmask = (1ull << lane) - 1ull;
    u32 dg[16], pk[16];
    volatile u16* vwh = wh;
    #pragma unroll 2
    for (int i = 0; i < 16; ++i) {
        u32 d = (u32)(v[i] >> SHIFT) & (NB - 1);
        u64 m = matchN<10>(d);
        u32 before = (u32)__popcll(m & ltmask);
        u32 cnt = (u32)__popcll(m);
        bool lead = (lane == __ffsll((unsigned long long)m) - 1);
        dg[i] = d;
        pk[i] = before | (cnt << 8) | (lead ? 0x10000u : 0u);
        if (lead) { u32 p = d * 4 + w; vwh[p] = (u16)(vwh[p] + cnt); }
    }
    __syncthreads();
    block_scan<NB>((const u32*)el, (const u32*)el + NB, wh, dl, aux, tid, lane, w);
    __syncthreads();

    for (int i = 0; i < 16; ++i) {
        u32 d = dg[i];
        u32 before = pk[i] & 0xffu;
        u32 base = vwh[d * 4 + w];
        el[base + before] = v[i];
        if (pk[i] & 0x10000u) vwh[d * 4 + w] = (u16)(base + ((pk[i] >> 8) & 0xffu));
    }
    __syncthreads();

    if (!COMPRESS) {
        u64* dst = (u64*)outbuf + (size_t)s * Pp;
        for (int i = 0; i < 16; ++i) {
            int pos = i * 256 + tid;
            u64 e = el[pos];
            u32 d = (u32)(e >> SHIFT) & (NB - 1);
            u32 g = (u32)(u16)(pos + dl[d]);
            dst[g] = e;
        }
    } else {
        u32* dst = (u32*)outbuf + (size_t)s * Pp;
        for (int i = 0; i < 16; ++i) {
            int pos = i * 256 + tid;
            u64 e = el[pos];
            u32 d = (u32)(e >> SHIFT) & (NB - 1);
            u32 g = (u32)(u16)(pos + dl[d]);
            dst[g] = ((u32)(e >> 36) << 16) | (u32)(e & 0xffffu);   // key[36,47) | idx
        }
    }
}

// ---------------------------------------------------------------------------
// Final scatter (u32, 11-bit top digit): rank -> g; emit out[s][g] =
// coords[s][idx] for g < K; fused extra_random copy into rows [K, P).
// 36 KB LDS -> 4 blocks/CU.
// ---------------------------------------------------------------------------
__global__ __launch_bounds__(256) void scatter32_final_kernel(const u32* __restrict__ in,
                                                              const u32* __restrict__ hist,
                                                              const float2* __restrict__ coords,
                                                              const float2* __restrict__ extra,
                                                              float2* __restrict__ out) {
    __shared__ u32 el32[TILE];         // 16 KB (= scan scratch pre-B: sc1|sc2)
    __shared__ u16 wh[NB2 * 4];        // 16 KB
    __shared__ u16 dl[NB2];            // 4 KB
    __shared__ u64 aux[4];
    const int tid = threadIdx.x;
    const int lane = tid & 63;
    const int w = tid >> 6;
    const int blk = blockIdx.x;
    DECODE_ST
    const u32* src = in + (size_t)s * Pp + t * TILE;

    for (int i = tid; i < NB2 * 4; i += 256) wh[i] = 0;
    u32 v[16];
    #pragma unroll
    for (int i = 0; i < 16; ++i) v[i] = src[w * 1024 + i * 64 + lane];
    fill_seg_tables<NB2>((u32*)el32, (u32*)el32 + NB2, hist + (size_t)s * (TILES * NB2), t, tid);
    __syncthreads();

    const u64 ltmask = (1ull << lane) - 1ull;
    u32 dg[16], pk[16];
    volatile u16* vwh = wh;
    #pragma unroll 2
    for (int i = 0; i < 16; ++i) {
        u32 d = (v[i] >> 16) & (NB2 - 1);
        u64 m = matchN<11>(d);
        u32 before = (u32)__popcll(m & ltmask);
        u32 cnt = (u32)__popcll(m);
        bool lead = (lane == __ffsll((unsigned long long)m) - 1);
        dg[i] = d;
        pk[i] = before | (cnt << 8) | (lead ? 0x10000u : 0u);
        if (lead) { u32 p = d * 4 + w; vwh[p] = (u16)(vwh[p] + cnt); }
    }
    __syncthreads();
    block_scan<NB2>((const u32*)el32, (const u32*)el32 + NB2, wh, dl, aux, tid, lane, w);
    __syncthreads();

    for (int i = 0; i < 16; ++i) {
        u32 d = dg[i];
        u32 before = pk[i] & 0xffu;
        u32 base = vwh[d * 4 + w];
        el32[base + before] = v[i];
        if (pk[i] & 0x10000u) vwh[d * 4 + w] = (u16)(base + ((pk[i] >> 8) & 0xffu));
    }
    __syncthreads();

    const float2* cseg = coords + (size_t)s * Pp;
    float2* oseg = out + (size_t)s * Pp;
    for (int i = 0; i < 16; ++i) {
        int pos = i * 256 + tid;
        u32 e = el32[pos];
        u32 d = (e >> 16) & (NB2 - 1);
        u32 g = (u32)(u16)(pos + dl[d]);
        if (g < Kk) oseg[g] = cseg[e & 0xffffu];
    }
    const float2* eseg = extra + (size_t)s * NR;
    float2* xseg = out + (size_t)s * Pp + Kk;
    #pragma unroll
    for (int i = 0; i < 4; ++i) {
        int p = t * 1024 + i * 256 + tid;
        xseg[p] = eseg[p];
    }
}

extern "C" void kernel_launch(void* const* d_in, const int* in_sizes, int n_in,
                              void* d_out, int out_size, void* d_ws, size_t ws_size,
                              hipStream_t stream) {
    (void)in_sizes; (void)n_in; (void)out_size; (void)ws_size;
    const float*  logits = (const float*)d_in[0];   // (B,H,W,C) fp32
    const float2* coords = (const float2*)d_in[1];  // (B,P,2)  fp32
    const float2* extra  = (const float2*)d_in[2];  // (B,NR,2) fp32
    float2* out = (float2*)d_out;

    u64* buf0 = (u64*)d_ws;                          // 25.2 MB
    u64* buf1 = buf0 + (size_t)Bb * Pp;              // 25.2 MB (ping-pong)
    float* planes = (float*)buf1;                    // 4 MB; dead before pass-0 scatter writes buf1
    u32* histA = (u32*)d_out;                        // 3.1 MB scratch (passes 0,1); final pass overwrites all of out
    u32* histB = (u32*)buf1;                         // pass-2 hist (6.3 MB); buf1 keys dead after pass-1 scatter

    // ch-0 extract (dense float4) -> compact planes
    extract_kernel<<<1024, 256, 0, stream>>>(logits, planes);
    // sample: planes,coords -> keys(buf0,u64) + pass-0 hist (10-bit)
    sample_key_kernel<<<NBLK, 256, 0, stream>>>(planes, coords, buf0, histA);
    // pass 0: bits [16,26)  buf0(u64) -> buf1(u64)
    scatter64_kernel<NB0, 16, false><<<NBLK, 256, 0, stream>>>(buf0, buf1, histA);
    // pass 1: bits [26,36)  buf1(u64) -> buf0(u32 compressed: key[36,47)|idx)
    hist64_kernel<<<NBLK, 256, 0, stream>>>(buf1, histA, 26);
    scatter64_kernel<NB0, 26, true><<<NBLK, 256, 0, stream>>>(buf1, buf0, histA);
    // pass 2: 11-bit top digit  buf0(u32) -> out (fused gather+emit+extra)
    hist32_kernel<<<NBLK, 256, 0, stream>>>((const u32*)buf0, histB);
    scatter32_final_kernel<<<NBLK, 256, 0, stream>>>((const u32*)buf0, histB, coords, extra, out);
}

// Round 8
// 256.676 us; speedup vs baseline: 1.1722x; 1.0533x over previous
//
#include <hip/hip_runtime.h>
#include <stdint.h>

#define Bb 64
#define Hh 128
#define Ww 128
#define Cc 21
#define Pp 49152          // NUM_SAMPLED
#define Kk 36864          // NUM_UNCERTAIN
#define NR 12288          // NUM_RANDOM

// Digit split 10/10/11 over key bits [16,47): passes 0,1 use 10-bit digits
// (write runs ~4 -> half the scattered-write line traffic of 11/11/9);
// pass 2 gets the 11-bit exponent-dominated digit (skewed -> long runs).
#define NB0 1024          // pass 0/1 bins
#define NB2 2048          // pass 2 bins
#define TILE 4096         // elements per sort tile
#define TILES 12          // Pp / TILE
#define NBLK (Bb * TILES) // 768 blocks
#define NTHR 512          // 8 waves/block: same LDS/tile, 2x waves/CU (R7 lesson:
                          // bodies are latency-bound at 12 waves/CU; LDS caps
                          // blocks/CU, so bigger blocks = free occupancy)

typedef uint32_t u32;
typedef uint64_t u64;
typedef unsigned short u16;

// XCD-affine decode: all TILES blocks of segment s have blk%8 == s%8 ->
// segment's r/w window stays in one XCD's L2. Heuristic only.
#define DECODE_ST const int s = blk & 63; const int t = blk >> 6;

// N-bit ballot digit-match: mask of lanes in this wave holding digit d.
template<int NBITS>
__device__ __forceinline__ u64 matchN(u32 d) {
    u64 m = ~0ull;
    #pragma unroll
    for (int bit = 0; bit < NBITS; ++bit) {
        u64 bl = __ballot((d >> bit) & 1u);
        m &= ((d >> bit) & 1u) ? bl : ~bl;
    }
    return m;
}

// ---------------------------------------------------------------------------
// Kernel 0: vectorized ch-0 extract. Dense float4 reads (R4 lesson: 84B-
// strided scalar reads are latency-bound at 1.8 TB/s; dense float4 ~6 TB/s).
// ---------------------------------------------------------------------------
__global__ __launch_bounds__(256) void extract_kernel(const float* __restrict__ lg,
                                                      float* __restrict__ planes) {
    const u32 gtid = blockIdx.x * 256 + threadIdx.x;   // [0, 262144)
    const float4* l4 = (const float4*)lg;
    #pragma unroll
    for (u32 it = 0; it < 21; ++it) {
        u32 g = it * 262144u + gtid;                   // [0, 5505024)
        float4 v = l4[g];
        u32 base = g * 4u;
        u32 k = (base + 20u) / 21u;                    // first px with ch0 >= base
        u32 pos = k * 21u - base;
        if (pos < 4u) {
            float val = (pos == 0u) ? v.x : (pos == 1u) ? v.y : (pos == 2u) ? v.z : v.w;
            planes[k] = val;
        }
    }
}

// ---------------------------------------------------------------------------
// Kernel 1: bilinear sample (64 KB compact plane staged via float4), key
// build, fused pass-0 (10-bit) hist. 512 thr -> 16 waves/CU (was 8).
// key = fp32 bits of |interp| (order-isomorphic, non-negative); element =
// (key<<16)|idx; LSD stability supplies the idx tie-break (jax.lax.top_k).
// fp contract OFF: bit-exact arithmetic required.
// ---------------------------------------------------------------------------
__global__ __launch_bounds__(512, 4) void sample_key_kernel(const float* __restrict__ planes,
                                                            const float2* __restrict__ coords,
                                                            u64* __restrict__ keys,
                                                            u32* __restrict__ hist) {
#pragma clang fp contract(off)
    __shared__ float pl[Hh * Ww];      // 64 KB
    __shared__ u32 h[NB0];             // 4 KB
    const int tid = threadIdx.x;
    const int blk = blockIdx.x;
    DECODE_ST

    for (int i = tid; i < NB0; i += NTHR) h[i] = 0;
    const float4* p4 = (const float4*)(planes + (size_t)s * (Hh * Ww));
    float4* l4 = (float4*)pl;
    #pragma unroll
    for (int i = 0; i < 8; ++i) l4[i * NTHR + tid] = p4[i * NTHR + tid];
    __syncthreads();

    #pragma unroll 4
    for (int i = 0; i < 8; ++i) {
        int idx = t * TILE + i * NTHR + tid;           // point index within segment
        int gid = s * Pp + idx;
        float2 c = coords[gid];
        float xf = c.x * 127.0f;                       // coords[...,0] -> H axis
        float yf = c.y * 127.0f;                       // coords[...,1] -> W axis
        float x0 = floorf(xf), x1 = ceilf(xf);
        float y0 = floorf(yf), y1 = ceilf(yf);
        float mux = xf - x0;
        float muy = yf - y0;
        int x0i = (int)x0, x1i = (int)x1, y0i = (int)y0, y1i = (int)y1;
        float p1  = pl[x0i * Ww + y0i];
        float p2  = pl[x1i * Ww + y0i];
        float p3  = pl[x0i * Ww + y1i];
        float p4v = pl[x1i * Ww + y1i];
        float p12 = p1 * (1.0f - mux) + p2 * mux;
        float p34 = p3 * (1.0f - mux) + p4v * mux;
        float r   = p12 * (1.0f - muy) + p34 * muy;
        u32 kb = __float_as_uint(r) & 0x7fffffffu;     // |r| bits
        keys[gid] = ((u64)kb << 16) | (u32)idx;
        atomicAdd(&h[kb & (NB0 - 1)], 1u);             // pass-0 digit (uniform)
    }
    __syncthreads();
    const size_t hbase = ((size_t)s * TILES + t) * NB0;
    for (int d = tid; d < NB0; d += NTHR) hist[hbase + d] = h[d];
}

// ---------------------------------------------------------------------------
// hist64: per-wave privatized tables (8 waves x 1024 bins, uniform digit ->
// negligible collisions). Output layout [s][t][d] (tile-major, coalesced).
// ---------------------------------------------------------------------------
__global__ __launch_bounds__(512, 8) void hist64_kernel(const u64* __restrict__ in,
                                                        u32* __restrict__ hist, int shift) {
    __shared__ u32 h[8][NB0];          // 32 KB
    const int tid = threadIdx.x;
    const int w = tid >> 6;
    const int blk = blockIdx.x;
    DECODE_ST
    for (int i = tid; i < 8 * NB0; i += NTHR) ((u32*)h)[i] = 0;
    __syncthreads();
    const u64* src = in + (size_t)s * Pp + t * TILE;
    #pragma unroll 4
    for (int i = 0; i < 8; ++i) {
        u64 v = src[i * NTHR + tid];
        atomicAdd(&h[w][(u32)(v >> shift) & (NB0 - 1)], 1u);
    }
    __syncthreads();
    const size_t hbase = ((size_t)s * TILES + t) * NB0;
    for (int d = tid; d < NB0; d += NTHR) {
        u32 sum = 0;
        #pragma unroll
        for (int k = 0; k < 8; ++k) sum += h[k][d];
        hist[hbase + d] = sum;
    }
}

// hist32 stays 256-thr/4-table: pass-2 digit is SKEWED; 8 waves on shared
// tables would double hot-bin atomic serialization.
__global__ __launch_bounds__(256) void hist32_kernel(const u32* __restrict__ in,
                                                     u32* __restrict__ hist) {
    __shared__ u32 h[4][NB2];          // 32 KB
    const int tid = threadIdx.x;
    const int w = tid >> 6;
    const int blk = blockIdx.x;
    DECODE_ST
    for (int i = tid; i < 4 * NB2; i += 256) ((u32*)h)[i] = 0;
    __syncthreads();
    const u32* src = in + (size_t)s * Pp + t * TILE;
    #pragma unroll 4
    for (int i = 0; i < 16; ++i) {
        u32 v = src[i * 256 + tid];
        atomicAdd(&h[w][(v >> 16) & (NB2 - 1)], 1u);   // 11-bit top digit
    }
    __syncthreads();
    const size_t hbase = ((size_t)s * TILES + t) * NB2;
    #pragma unroll
    for (int j = 0; j < NB2 / 256; ++j) {
        int d = j * 256 + tid;
        hist[hbase + d] = h[0][d] + h[1][d] + h[2][d] + h[3][d];
    }
}

// ---------------------------------------------------------------------------
// Offset derivation: raw per-tile hist [s][t][d] ->
//   off[s][d][t] = sum_{d'<d} segtot[d'] + sum_{t'<t} cnt[d][t']
// Seg tables staged in scan scratch (head of el, dead until phase B); dual
// block-scan packed in u64 (local count low, segment count high; no carry).
// ---------------------------------------------------------------------------
template<int NB>
__device__ __forceinline__ void fill_seg_tables(u32* sc1v, u32* sc2v,
                                                const u32* hb, int t, int tid) {
    for (int d = tid; d < NB; d += NTHR) {
        u32 tot = 0, pre = 0;
        #pragma unroll
        for (int tt = 0; tt < TILES; ++tt) {
            u32 cv = hb[tt * NB + d];       // coalesced, L2-hot
            tot += cv;
            pre += (tt < t) ? cv : 0;
        }
        sc1v[d] = tot;
        sc2v[d] = pre;
    }
}

// wh layout: [digit][8 waves] u16. dl[d] = off - local_start (mod 2^16, exact
// since Pp < 65536).
template<int NB>
__device__ __forceinline__ void block_scan(const u32* sc1v, const u32* sc2v,
                                           u16* wh, u16* dl, u64* aux,
                                           int tid, int lane, int w) {
    constexpr int DPB = NB / NTHR;          // digits per thread (2 or 4)
    const int d0 = tid * DPB;
    u32 dtot[DPB], gtot[DPB], gpre[DPB];
    u32 t8l = 0, t8g = 0;
    #pragma unroll
    for (int j = 0; j < DPB; ++j) {
        int d = d0 + j;
        u32 cv = 0;
        #pragma unroll
        for (int k = 0; k < 8; ++k) cv += wh[d * 8 + k];
        dtot[j] = cv; t8l += cv;
        gtot[j] = sc1v[d]; gpre[j] = sc2v[d]; t8g += gtot[j];
    }
    u64 own = ((u64)t8g << 32) | t8l;
    u64 sc = own;
    for (int o = 1; o < 64; o <<= 1) {
        u64 n = __shfl_up((unsigned long long)sc, o);
        if (lane >= o) sc += n;
    }
    if (lane == 63) aux[w] = sc;
    __syncthreads();
    if (tid == 0) {
        u64 run = 0;
        #pragma unroll
        for (int i = 0; i < 8; ++i) { u64 x = aux[i]; aux[i] = run; run += x; }
    }
    __syncthreads();
    u64 excl = sc - own + aux[w];
    u32 run_l = (u32)excl;                  // local exclusive base
    u32 run_g = (u32)(excl >> 32);          // segment digit-exclusive base
    #pragma unroll
    for (int j = 0; j < DPB; ++j) {
        int d = d0 + j;
        u32 ls = run_l;
        u32 g = run_g + gpre[j];            // off[s][d][t]
        dl[d] = (u16)(g - ls);
        u32 acc = ls;
        #pragma unroll
        for (int k = 0; k < 8; ++k) {
            u32 ck = wh[d * 8 + k];
            wh[d * 8 + k] = (u16)acc;
            acc += ck;
        }
        run_l += dtot[j];
        run_g += gtot[j];
    }
}

// ---------------------------------------------------------------------------
// Scatter (u64 passes 0,1): stable LDS reorder + run-contiguous global write.
// 512 thr, 8 els/thread -> 24 waves/CU (was 12). matchN once per element;
// cached ranks reused in phase B. COMPRESS (pass 1): emit u32
// (key[36,47)<<16)|idx — bits [16,36) spent; halves pass-2 traffic.
// LDS: 32K el + 16K wh + 2K dl = 51.3 KB -> 3 blocks/CU (153.8 <= 160).
// ---------------------------------------------------------------------------
template<int SHIFT, bool COMPRESS>
__global__ __launch_bounds__(512, 6) void scatter64_kernel(const u64* __restrict__ in,
                                                           void* __restrict__ outbuf,
                                                           const u32* __restrict__ hist) {
    __shared__ u64 el[TILE];           // 32 KB (head = scan scratch pre-B)
    __shared__ u16 wh[NB0 * 8];        // 16 KB  [digit][wave]
    __shared__ u16 dl[NB0];            // 2 KB
    __shared__ u64 aux[8];
    const int tid = threadIdx.x;
    const int lane = tid & 63;
    const int w = tid >> 6;
    const int blk = blockIdx.x;
    DECODE_ST
    const u64* src = in + (size_t)s * Pp + t * TILE;

    for (int i = tid; i < NB0 * 4; i += NTHR) ((u32*)wh)[i] = 0;
    u64 v[8];
    #pragma unroll
    for (int i = 0; i < 8; ++i) v[i] = src[w * 512 + i * 64 + lane];
    fill_seg_tables<NB0>((u32*)el, (u32*)el + NB0, hist + (size_t)s * (TILES * NB0), t, tid);
    __syncthreads();

    const u64 ltmask = (1ull << lane) - 1ull;
    u32 dg[8], pk[8];
    volatile u16* vwh = wh;
    #pragma unroll 2
    for (int i = 0; i < 8; ++i) {
        u32 d = (u32)(v[i] >> SHIFT) & (NB0 - 1);
        u64 m = matchN<10>(d);
        u32 before = (u32)__popcll(m & ltmask);
        u32 cnt = (u32)__popcll(m);
        bool lead = (lane == __ffsll((unsigned long long)m) - 1);
        dg[i] = d;
        pk[i] = before | (cnt << 8) | (lead ? 0x10000u : 0u);
        if (lead) { u32 p = d * 8 + w; vwh[p] = (u16)(vwh[p] + cnt); }
    }
    __syncthreads();
    block_scan<NB0>((const u32*)el, (const u32*)el + NB0, wh, dl, aux, tid, lane, w);
    __syncthreads();

    for (int i = 0; i < 8; ++i) {
        u32 d = dg[i];
        u32 before = pk[i] & 0xffu;
        u32 base = vwh[d * 8 + w];
        el[base + before] = v[i];
        if (pk[i] & 0x10000u) vwh[d * 8 + w] = (u16)(base + ((pk[i] >> 8) & 0xffu));
    }
    __syncthreads();

    if (!COMPRESS) {
        u64* dst = (u64*)outbuf + (size_t)s * Pp;
        for (int i = 0; i < 8; ++i) {
            int pos = i * NTHR + tid;
            u64 e = el[pos];
            u32 d = (u32)(e >> SHIFT) & (NB0 - 1);
            u32 g = (u32)(u16)(pos + dl[d]);
            dst[g] = e;
        }
    } else {
        u32* dst = (u32*)outbuf + (size_t)s * Pp;
        for (int i = 0; i < 8; ++i) {
            int pos = i * NTHR + tid;
            u64 e = el[pos];
            u32 d = (u32)(e >> SHIFT) & (NB0 - 1);
            u32 g = (u32)(u16)(pos + dl[d]);
            dst[g] = ((u32)(e >> 36) << 16) | (u32)(e & 0xffffu);   // key[36,47) | idx
        }
    }
}

// ---------------------------------------------------------------------------
// Final scatter (u32, 11-bit top digit): rank -> g; emit out[s][g] =
// coords[s][idx] for g < K; fused extra_random copy into rows [K, P).
// LDS: 16K el32 + 32K wh + 4K dl = 53.3 KB -> 3 blocks/CU (159.9 <= 160).
// ---------------------------------------------------------------------------
__global__ __launch_bounds__(512, 6) void scatter32_final_kernel(const u32* __restrict__ in,
                                                                 const u32* __restrict__ hist,
                                                                 const float2* __restrict__ coords,
                                                                 const float2* __restrict__ extra,
                                                                 float2* __restrict__ out) {
    __shared__ u32 el32[TILE];         // 16 KB (head = scan scratch pre-B)
    __shared__ u16 wh[NB2 * 8];        // 32 KB
    __shared__ u16 dl[NB2];            // 4 KB
    __shared__ u64 aux[8];
    const int tid = threadIdx.x;
    const int lane = tid & 63;
    const int w = tid >> 6;
    const int blk = blockIdx.x;
    DECODE_ST
    const u32* src = in + (size_t)s * Pp + t * TILE;

    for (int i = tid; i < NB2 * 4; i += NTHR) ((u32*)wh)[i] = 0;
    u32 v[8];
    #pragma unroll
    for (int i = 0; i < 8; ++i) v[i] = src[w * 512 + i * 64 + lane];
    fill_seg_tables<NB2>((u32*)el32, (u32*)el32 + NB2, hist + (size_t)s * (TILES * NB2), t, tid);
    __syncthreads();

    const u64 ltmask = (1ull << lane) - 1ull;
    u32 dg[8], pk[8];
    volatile u16* vwh = wh;
    #pragma unroll 2
    for (int i = 0; i < 8; ++i) {
        u32 d = (v[i] >> 16) & (NB2 - 1);
        u64 m = matchN<11>(d);
        u32 before = (u32)__popcll(m & ltmask);
        u32 cnt = (u32)__popcll(m);
        bool lead = (lane == __ffsll((unsigned long long)m) - 1);
        dg[i] = d;
        pk[i] = before | (cnt << 8) | (lead ? 0x10000u : 0u);
        if (lead) { u32 p = d * 8 + w; vwh[p] = (u16)(vwh[p] + cnt); }
    }
    __syncthreads();
    block_scan<NB2>((const u32*)el32, (const u32*)el32 + NB2, wh, dl, aux, tid, lane, w);
    __syncthreads();

    for (int i = 0; i < 8; ++i) {
        u32 d = dg[i];
        u32 before = pk[i] & 0xffu;
        u32 base = vwh[d * 8 + w];
        el32[base + before] = v[i];
        if (pk[i] & 0x10000u) vwh[d * 8 + w] = (u16)(base + ((pk[i] >> 8) & 0xffu));
    }
    __syncthreads();

    const float2* cseg = coords + (size_t)s * Pp;
    float2* oseg = out + (size_t)s * Pp;
    for (int i = 0; i < 8; ++i) {
        int pos = i * NTHR + tid;
        u32 e = el32[pos];
        u32 d = (e >> 16) & (NB2 - 1);
        u32 g = (u32)(u16)(pos + dl[d]);
        if (g < Kk) oseg[g] = cseg[e & 0xffffu];
    }
    const float2* eseg = extra + (size_t)s * NR;
    float2* xseg = out + (size_t)s * Pp + Kk;
    #pragma unroll
    for (int i = 0; i < 2; ++i) {
        int p = t * 1024 + i * NTHR + tid;
        xseg[p] = eseg[p];
    }
}

extern "C" void kernel_launch(void* const* d_in, const int* in_sizes, int n_in,
                              void* d_out, int out_size, void* d_ws, size_t ws_size,
                              hipStream_t stream) {
    (void)in_sizes; (void)n_in; (void)out_size; (void)ws_size;
    const float*  logits = (const float*)d_in[0];   // (B,H,W,C) fp32
    const float2* coords = (const float2*)d_in[1];  // (B,P,2)  fp32
    const float2* extra  = (const float2*)d_in[2];  // (B,NR,2) fp32
    float2* out = (float2*)d_out;

    u64* buf0 = (u64*)d_ws;                          // 25.2 MB
    u64* buf1 = buf0 + (size_t)Bb * Pp;              // 25.2 MB (ping-pong)
    float* planes = (float*)buf1;                    // 4 MB; dead before pass-0 scatter writes buf1
    u32* histA = (u32*)d_out;                        // 3.1 MB scratch (passes 0,1); final pass overwrites all of out
    u32* histB = (u32*)buf1;                         // pass-2 hist (6.3 MB); buf1 keys dead after pass-1 scatter

    // ch-0 extract (dense float4) -> compact planes
    extract_kernel<<<1024, 256, 0, stream>>>(logits, planes);
    // sample: planes,coords -> keys(buf0,u64) + pass-0 hist (10-bit)
    sample_key_kernel<<<NBLK, NTHR, 0, stream>>>(planes, coords, buf0, histA);
    // pass 0: bits [16,26)  buf0(u64) -> buf1(u64)
    scatter64_kernel<16, false><<<NBLK, NTHR, 0, stream>>>(buf0, buf1, histA);
    // pass 1: bits [26,36)  buf1(u64) -> buf0(u32 compressed: key[36,47)|idx)
    hist64_kernel<<<NBLK, NTHR, 0, stream>>>(buf1, histA, 26);
    scatter64_kernel<26, true><<<NBLK, NTHR, 0, stream>>>(buf1, buf0, histA);
    // pass 2: 11-bit top digit  buf0(u32) -> out (fused gather+emit+extra)
    hist32_kernel<<<NBLK, 256, 0, stream>>>((const u32*)buf0, histB);
    scatter32_final_kernel<<<NBLK, NTHR, 0, stream>>>((const u32*)buf0, histB, coords, extra, out);
}